// Round 6
// baseline (80.052 us; speedup 1.0000x reference)
//
#include <hip/hip_runtime.h>
#include <stdint.h>

namespace {

constexpr int   B_    = 64;
constexpr int   F0_   = 1876;
constexpr int   F1_   = 1024;
constexpr int   F2_   = 10;
constexpr int   NT_   = 151;
constexpr float DT_   = 0.02f;
constexpr int   NSTR_ = 2048;     // padded stream (8 chunks of 256)
constexpr int   CHUNK_= 256;
constexpr int   NGRP_ = 32;       // groups of 8 per chunk
constexpr int   NB1_  = 51;       // real bins 0..50
constexpr float SCL_  = 67108864.0f;       // 2^26 fixed-point scale
constexpr float ISCL_ = 1.0f / 67108864.0f;

// workspace layout (bytes)
constexpr size_t OFF_W1T  = 0;                           // 1877*1024*4 = 7,688,192
constexpr size_t OFF_PAIR = 7688192;                     // 64*2048*8   = 1,048,576
constexpr size_t OFF_IDX1 = OFF_PAIR + 1048576;          // 64*1024 u8  =    65,536

// ---------------------------------------------------------------------------
// W1[j][i] (1024x1876 f32) -> W1T[i][j] (1877x1024 f32), row 1876 zero.
// ---------------------------------------------------------------------------
__global__ __launch_bounds__(256) void k_w1t(const float* __restrict__ W1,
                                             float* __restrict__ W1T) {
  __shared__ float tile[64][65];
  const int i0 = blockIdx.x * 64;   // 30 tiles -> rows 0..1919
  const int j0 = blockIdx.y * 64;   // 16 tiles
  const int t  = threadIdx.x;
  const int c  = t & 63, r4 = t >> 6;
  for (int jj = r4; jj < 64; jj += 4) {
    int i = i0 + c;
    float v = (i < F0_) ? W1[(size_t)(j0 + jj) * F0_ + i] : 0.0f;
    tile[c][jj] = v;
  }
  __syncthreads();
  for (int ii = r4; ii < 64; ii += 4) {
    int i = i0 + ii;
    if (i <= F0_) W1T[(size_t)i * F1_ + j0 + c] = tile[ii][c];
  }
}

// ---------------------------------------------------------------------------
// Deterministic stable counting sort of ti by bin k = ceil(ti*50), per batch.
// 64 blocks x 256 threads. Emits sPair[b][pos] = { (i<<12)|k , ti_bits },
// padded to NSTR_ with dummies (row 1876 = zero weights, bin 80).
// ---------------------------------------------------------------------------
__global__ __launch_bounds__(256) void k_sort1(const float* __restrict__ ti,
                                               uint2* __restrict__ sPair) {
  __shared__ uint32_t hist[256][NB1_];
  __shared__ uint32_t bstart[NB1_ + 1];
  const int b = blockIdx.x, t = threadIdx.x;
  for (int k = 0; k < NB1_; ++k) hist[t][k] = 0;
  __syncthreads();

  const float* tib = ti + (size_t)b * F0_;
  const int n0 = t * 8;
  const int n1 = (n0 + 8 < F0_) ? n0 + 8 : F0_;
  for (int n = n0; n < n1; ++n) {
    int k = (int)ceilf(tib[n] * 50.0f);
    k = k < 0 ? 0 : (k > 50 ? 50 : k);
    hist[t][k]++;
  }
  __syncthreads();

  if (t < NB1_) {                    // column-wise exclusive prefix over chunks
    uint32_t run = 0;
    for (int c = 0; c < 256; ++c) { uint32_t x = hist[c][t]; hist[c][t] = run; run += x; }
    bstart[t + 1] = run;
  }
  __syncthreads();
  if (t == 0) {
    bstart[0] = 0;
    uint32_t acc = 0;
    for (int k = 0; k < NB1_; ++k) { uint32_t c = bstart[k + 1]; bstart[k + 1] = acc + c; acc += c; }
  }
  __syncthreads();

  uint2* out = sPair + (size_t)b * NSTR_;
  for (int n = n0; n < n1; ++n) {
    float v = tib[n];
    int k = (int)ceilf(v * 50.0f);
    k = k < 0 ? 0 : (k > 50 ? 50 : k);
    uint32_t pos = bstart[k] + hist[t][k]++;
    out[pos] = make_uint2(((uint32_t)n << 12) | (uint32_t)k, __float_as_uint(v));
  }
  for (int s = t; s < NSTR_ - F0_; s += 256)
    out[F0_ + s] = make_uint2(((uint32_t)F0_ << 12) | 80u, __float_as_uint(1.6f));
}

// ---------------------------------------------------------------------------
// Layer-1 main: 512 blocks = (b major, jp minor), 8 waves of 64 each.
// jp selects a 128-column slice of W1T; lane covers j = jp*128 + 2*lane, +1
// via float2 loads. Wave wv walks sorted-stream chunk [wv*256, wv*256+256):
// scalar (uniform) pair stream + per-lane float2 weight loads, register
// (SA,SC) pairs; per-bin deltas dumped at (uniform, rare) bin boundaries into
// LDS as FIXED-POINT int32 atomics (order-independent -> bit-deterministic).
// Depth-4 pair pipeline; weights issued 2 groups ahead of consumption.
// Phase 2: prefix over bins, (t-quarter, j-half) per wave, min-reduce.
// ---------------------------------------------------------------------------
__global__ __launch_bounds__(512) void k_main1(const uint2* __restrict__ sPair,
                                               const float* __restrict__ W1T,
                                               uint8_t* __restrict__ idx1) {
  __shared__ int binAi[NB1_][128];
  __shared__ int binCi[NB1_][128];
  __shared__ int cand[4][128];
  const int blk  = blockIdx.x;      // 512
  const int b    = blk >> 3;
  const int jp   = blk & 7;
  const int tid  = threadIdx.x;
  const int lane = tid & 63;
  const int wv   = __builtin_amdgcn_readfirstlane(tid >> 6);  // 0..7, SGPR

  {
    int4* p = (int4*)(&binAi[0][0]);
    const int ntot = (NB1_ * 128 * 2) / 4;       // 3264 int4
    for (int s = tid; s < ntot; s += 512) p[s] = make_int4(0, 0, 0, 0);
  }
  __syncthreads();

  const uint2* __restrict__ spw = sPair + (size_t)b * NSTR_ + wv * CHUNK_;
  const char*  __restrict__ wb  = (const char*)W1T;
  const uint32_t col8 = (uint32_t)(jp * 512 + lane * 8);  // byte offset in row

  float SA0 = 0.f, SC0 = 0.f, SA1 = 0.f, SC1 = 0.f;
  float SA0p = 0.f, SC0p = 0.f, SA1p = 0.f, SC1p = 0.f;
  uint32_t kcur;

  uint2  Pb[4][8];   // wave-uniform pair stream (SGPRs)
  float2 W[4][8];    // per-lane weight pairs

#define RDP(buf, g) {                                                         \
  _Pragma("unroll") for (int e = 0; e < 8; ++e) Pb[buf][e] = spw[(g) * 8 + e]; }

#define ISSW(buf) {                                                           \
  _Pragma("unroll") for (int e = 0; e < 8; ++e) {                             \
    W[buf][e] = *(const float2*)(wb + (Pb[buf][e].x & ~4095u) + col8); } }

#define DUMP() { if (kcur < (uint32_t)NB1_) {                                 \
    atomicAdd(&binAi[kcur][2 * lane],     __float2int_rn((SA0 - SA0p) * SCL_)); \
    atomicAdd(&binCi[kcur][2 * lane],     __float2int_rn((SC0 - SC0p) * SCL_)); \
    atomicAdd(&binAi[kcur][2 * lane + 1], __float2int_rn((SA1 - SA1p) * SCL_)); \
    atomicAdd(&binCi[kcur][2 * lane + 1], __float2int_rn((SC1 - SC1p) * SCL_)); } \
  SA0p = SA0; SC0p = SC0; SA1p = SA1; SC1p = SC1; }

#define PROC(buf) {                                                           \
  uint32_t kend = Pb[buf][7].x & 4095u;                                       \
  if (kend == kcur) {  /* fast path: bins sorted -> uniform group */          \
    _Pragma("unroll") for (int e = 0; e < 8; ++e) {                           \
      float2 w = W[buf][e];                                                   \
      float tiv = __uint_as_float(Pb[buf][e].y);                              \
      SA0 += w.x; SC0 = fmaf(w.x, tiv, SC0);                                  \
      SA1 += w.y; SC1 = fmaf(w.y, tiv, SC1); }                                \
  } else {                                                                    \
    _Pragma("unroll") for (int e = 0; e < 8; ++e) {                           \
      uint32_t kb = Pb[buf][e].x & 4095u;                                     \
      if (kb != kcur) { DUMP(); kcur = kb; }                                  \
      float2 w = W[buf][e];                                                   \
      float tiv = __uint_as_float(Pb[buf][e].y);                              \
      SA0 += w.x; SC0 = fmaf(w.x, tiv, SC0);                                  \
      SA1 += w.y; SC1 = fmaf(w.y, tiv, SC1); }                                \
  } }

// half-stage: P: b0=g, b1=g+1, b2=g+2, b3=g+3; W issued for g, g+1.
// After: P: b2..b3,b0,b1 = g+2..g+5; W issued g+2, g+3.
#define HALF(b0, b1, b2, b3, g)                                               \
  ISSW(b2); PROC(b0); RDP(b0, (g) + 4);                                       \
  ISSW(b3); PROC(b1); RDP(b1, (g) + 5);

  // prologue: pairs 4 groups deep, weights 2 deep
  RDP(0, 0); RDP(1, 1); RDP(2, 2); RDP(3, 3);
  ISSW(0); ISSW(1);
  kcur = Pb[0][0].x & 4095u;

#pragma unroll 1
  for (int g = 0; g <= NGRP_ - 8; g += 4) {   // g = 0,4,...,24
    HALF(0, 1, 2, 3, g);
    HALF(2, 3, 0, 1, g + 2);
  }
  // P: 0..3 = g 28..31; W issued 28, 29
  ISSW(2); PROC(0);
  ISSW(3); PROC(1);
  PROC(2); PROC(3);
  DUMP();        // final real bin (skipped if kcur is dummy bin 80)

#undef HALF
#undef PROC
#undef DUMP
#undef ISSW
#undef RDP

  __syncthreads();

  // phase 2: prefix over bins; wave wv = (tq<<1)|jh checks col jh*64+lane
  // over t in [tq*38, t1)
  {
    const int jh = wv & 1, tq = wv >> 1;
    const int col = jh * 64 + lane;
    float SA2 = 0.f, SC2 = 0.f;
    int cnd = 151;
    const int t0 = tq * 38;
    const int t1 = (tq == 3) ? NT_ : t0 + 38;
    for (int t = 0; t < t1; ++t) {
      if (t < NB1_) {
        SA2 += (float)binAi[t][col] * ISCL_;
        SC2 += (float)binCi[t][col] * ISCL_;
      }
      if (t >= t0 && cnd == 151) {
        float m = (float)t * DT_ * SA2 - SC2;
        if (m >= 1.0f) cnd = t;
      }
    }
    cand[tq][col] = cnd;
  }
  __syncthreads();
  if (tid < 128) {
    int id = min(min(cand[0][tid], cand[1][tid]),
                 min(cand[2][tid], cand[3][tid]));
    id = min(id, NT_ - 1);               // forced spike at last timestep
    idx1[((size_t)b << 10) + (jp << 7) + tid] = (uint8_t)id;
  }
}

// ---------------------------------------------------------------------------
// Layer-2: brute force. Block = (b,j), 4 waves split the i-range; lane = t.
// ---------------------------------------------------------------------------
__global__ __launch_bounds__(256) void k_main2(const uint8_t* __restrict__ idx1,
                                               const float* __restrict__ W2,
                                               float* __restrict__ out) {
  __shared__ float wrow[F1_];
  __shared__ float tirow[F1_];
  __shared__ float part[4][3][64];
  const int blk = blockIdx.x;          // 640
  const int b   = blk / 10;
  const int j   = blk - b * 10;
  const int tid = threadIdx.x;
  const int lane = tid & 63, wvv = tid >> 6;

  const float*   w = W2  + (size_t)j * F1_;
  const uint8_t* h = idx1 + (size_t)b * F1_;
  for (int s = tid; s < F1_; s += 256) {
    wrow[s]  = w[s];
    tirow[s] = (float)h[s] * DT_;
  }
  __syncthreads();

  const float tl0 = (float)lane * DT_;
  const float tl1 = (float)(lane + 64) * DT_;
  const float tl2 = (float)(lane + 128) * DT_;
  float m0 = 0.f, m1 = 0.f, m2 = 0.f;
  const int i0 = wvv * 256;
#pragma unroll 4
  for (int i = i0; i < i0 + 256; ++i) {
    float tiv = tirow[i], ww = wrow[i];
    m0 = fmaf(ww, fmaxf(tl0 - tiv, 0.f), m0);
    m1 = fmaf(ww, fmaxf(tl1 - tiv, 0.f), m1);
    m2 = fmaf(ww, fmaxf(tl2 - tiv, 0.f), m2);
  }
  part[wvv][0][lane] = m0;
  part[wvv][1][lane] = m1;
  part[wvv][2][lane] = m2;
  __syncthreads();

  if (wvv == 0) {
    m0 = part[0][0][lane] + part[1][0][lane] + part[2][0][lane] + part[3][0][lane];
    m1 = part[0][1][lane] + part[1][1][lane] + part[2][1][lane] + part[3][1][lane];
    m2 = part[0][2][lane] + part[1][2][lane] + part[2][2][lane] + part[3][2][lane];
    unsigned long long b0 = __ballot(m0 >= 1.0f);
    unsigned long long b1 = __ballot(m1 >= 1.0f);
    unsigned long long b2 = __ballot(m2 >= 1.0f);
    b2 &= (1ull << 23) - 1;            // t <= 150
    b2 |= (1ull << 22);                // forced spike at t = 150
    int tres;
    if (b0)      tres = __ffsll((long long)b0) - 1;
    else if (b1) tres = 64 + __ffsll((long long)b1) - 1;
    else         tres = 128 + __ffsll((long long)b2) - 1;
    if (lane == 0) out[(size_t)b * F2_ + j] = (float)tres * DT_;
  }
}

}  // namespace

// ---------------------------------------------------------------------------
extern "C" void kernel_launch(void* const* d_in, const int* in_sizes, int n_in,
                              void* d_out, int out_size, void* d_ws, size_t ws_size,
                              hipStream_t stream) {
  const float* ti = (const float*)d_in[0];   // [64][1876]
  const float* W1 = (const float*)d_in[1];   // [1024][1876]
  const float* W2 = (const float*)d_in[2];   // [10][1024]
  float* out = (float*)d_out;                // [64][10]

  char* ws = (char*)d_ws;
  float*   W1T  = (float*)(ws + OFF_W1T);
  uint2*   sPr  = (uint2*)(ws + OFF_PAIR);
  uint8_t* idx1 = (uint8_t*)(ws + OFF_IDX1);

  hipLaunchKernelGGL(k_w1t,   dim3(30, 16), dim3(256), 0, stream, W1, W1T);
  hipLaunchKernelGGL(k_sort1, dim3(64),     dim3(256), 0, stream, ti, sPr);
  hipLaunchKernelGGL(k_main1, dim3(512),    dim3(512), 0, stream, sPr, W1T, idx1);
  hipLaunchKernelGGL(k_main2, dim3(640),    dim3(256), 0, stream, idx1, W2, out);
}